// Round 5
// baseline (224.514 us; speedup 1.0000x reference)
//
#include <hip/hip_runtime.h>
#include <hip/hip_bf16.h>

#define DM 512
#define HEADS 8
#define DEPTH 64
#define BATCH 4
#define SEQ 8192
#define MROWS (BATCH*SEQ)

using short8 = __attribute__((ext_vector_type(8))) short;
using floatx4 = __attribute__((ext_vector_type(4))) float;

#define AS1 __attribute__((address_space(1)))
#define AS3 __attribute__((address_space(3)))

static __device__ __forceinline__ float bf2f(unsigned short u) {
    union { unsigned int i; float f; } x; x.i = ((unsigned int)u) << 16; return x.f;
}
static __device__ __forceinline__ unsigned short f2bf(float f) {
    union { float f; unsigned int i; } x; x.f = f;
    unsigned int i = x.i;
    return (unsigned short)((i + 0x7FFFu + ((i >> 16) & 1u)) >> 16);
}
static __device__ __forceinline__ unsigned int pack2(float a, float b) {
    return (unsigned int)f2bf(a) | ((unsigned int)f2bf(b) << 16);
}
static __device__ __forceinline__ void gl_lds16(const unsigned short* g, unsigned short* l) {
    __builtin_amdgcn_global_load_lds((const AS1 unsigned int*)g, (AS3 unsigned int*)l, 16, 0, 0);
}

// ---- W prep (merged): transpose + convert to bf16. wT[n][k] = w[k][n] ----
__global__ __launch_bounds__(256) void wprep_kernel(const float* __restrict__ wq,
                                                    const float* __restrict__ wk,
                                                    const float* __restrict__ wv,
                                                    unsigned short* __restrict__ wqT,
                                                    unsigned short* __restrict__ wkT,
                                                    unsigned short* __restrict__ wvT) {
    const float* w = blockIdx.y == 0 ? wq : (blockIdx.y == 1 ? wk : wv);
    unsigned short* wT = blockIdx.y == 0 ? wqT : (blockIdx.y == 1 ? wkT : wvT);
    int idx = blockIdx.x * 256 + threadIdx.x;
    int k = idx & (DM - 1);
    int n = idx >> 9;
    wT[n * DM + k] = f2bf(w[k * DM + n]);
}

// ---- Projection GEMM: Y[m][n] = phi?(X @ W + bias) as bf16 ----
// Tile 64(M) x 128(N), BK=64, double-buffered LDS, ONE barrier per K-step:
//   iter t: STAGE B(t+1) (gl_lds) + write A(t+1) regs->LDS + issue A(t+2) loads,
//           then ds_read frags + MFMA on buffers[t&1], then __syncthreads().
// Loads for t+1 overlap compute of t; the barrier's vmcnt(0) drain lands post-compute.
// 4 waves: wave w owns cols [w*32, w*32+32), all 64 rows. LDS 50KB -> 3 blocks/CU.
template<int PHI>
__global__ __launch_bounds__(256) void proj_kernel(const float* __restrict__ X,
                                                   const unsigned short* __restrict__ WT,
                                                   const float* __restrict__ bias,
                                                   unsigned short* __restrict__ Y) {
    __shared__ unsigned short As[2][64][72];      // 2 x 9 KiB (144 B rows)
    __shared__ unsigned short Bs[2][128 * 64];    // 2 x 16 KiB (swizzled contents)

    const int t = threadIdx.x;
    const int w = t >> 6;
    const int l15 = t & 15;
    const int g = (t >> 4) & 3;
    const int m0 = blockIdx.y * 64;
    const int n0 = blockIdx.x * 128;
    const int wc = w * 32;

    const int arow0 = t >> 3;
    const int arow1 = 32 + (t >> 3);
    const int acol = (t & 7) * 8;
    const float* xp0 = X + (size_t)(m0 + arow0) * DM + acol;
    const float* xp1 = X + (size_t)(m0 + arow1) * DM + acol;

    floatx4 acc[4][2] = {};
    float4 av0, av1, av2, av3;

    #define STAGE_B(tile, buf)                                                      \
        _Pragma("unroll")                                                           \
        for (int i = 0; i < 4; ++i) {                                               \
            int c = i * 256 + t;                                                    \
            int r = c >> 3, gp = c & 7, gd = gp ^ (r & 7);                          \
            const unsigned short* gsrc = WT + (size_t)(n0 + r) * DM + (tile) * 64 + gd * 8; \
            gl_lds16(gsrc, &Bs[buf][(i * 256 + w * 64) * 8]);                       \
        }

    #define LOAD_A(tile)                                                            \
        av0 = *(const float4*)(xp0 + (tile) * 64);                                  \
        av1 = *(const float4*)(xp0 + (tile) * 64 + 4);                              \
        av2 = *(const float4*)(xp1 + (tile) * 64);                                  \
        av3 = *(const float4*)(xp1 + (tile) * 64 + 4);

    #define WRITE_A(buf)                                                            \
        *(uint4*)&As[buf][arow0][acol] = make_uint4(pack2(av0.x, av0.y),            \
            pack2(av0.z, av0.w), pack2(av1.x, av1.y), pack2(av1.z, av1.w));         \
        *(uint4*)&As[buf][arow1][acol] = make_uint4(pack2(av2.x, av2.y),            \
            pack2(av2.z, av2.w), pack2(av3.x, av3.y), pack2(av3.z, av3.w));

    // prologue: tile 0 staged, tile 1's A in regs
    STAGE_B(0, 0);
    LOAD_A(0);
    WRITE_A(0);
    LOAD_A(1);
    __syncthreads();

    #pragma unroll
    for (int tile = 0; tile < 8; ++tile) {
        const int cur = tile & 1, nxt = cur ^ 1;
        if (tile < 7) {
            STAGE_B(tile + 1, nxt);
            WRITE_A(nxt);                 // regs hold A(tile+1), loaded last iter
            if (tile < 6) { LOAD_A(tile + 2); }
        }
        #pragma unroll
        for (int kk = 0; kk < 2; ++kk) {
            short8 af[4], bfr[2];
            #pragma unroll
            for (int m = 0; m < 4; ++m)
                af[m] = *(const short8*)&As[cur][m * 16 + l15][kk * 32 + g * 8];
            #pragma unroll
            for (int n = 0; n < 2; ++n) {
                int r = wc + n * 16 + l15;
                int ch = (kk * 4 + g) ^ (r & 7);
                bfr[n] = *(const short8*)(Bs[cur] + r * 64 + ch * 8);
            }
            #pragma unroll
            for (int m = 0; m < 4; ++m)
                #pragma unroll
                for (int n = 0; n < 2; ++n)
                    acc[m][n] = __builtin_amdgcn_mfma_f32_16x16x32_bf16(af[m], bfr[n], acc[m][n], 0, 0, 0);
        }
        __syncthreads();
    }

    // epilogue: C/D layout col=lane&15, row=(lane>>4)*4+reg  [verified m89/m91]
    #pragma unroll
    for (int n = 0; n < 2; ++n) {
        int col = n0 + wc + n * 16 + l15;
        float bv = bias[col];
        #pragma unroll
        for (int m = 0; m < 4; ++m) {
            #pragma unroll
            for (int j = 0; j < 4; ++j) {
                int row = m0 + m * 16 + g * 4 + j;
                float v = acc[m][n][j] + bv;
                if (PHI) v = (v > 0.0f) ? (v + 1.0f) : __expf(v);  // elu(x)+1
                Y[(size_t)row * DM + col] = f2bf(v);
            }
        }
    }
    #undef STAGE_B
    #undef LOAD_A
    #undef WRITE_A
}

// ---- kv einsum + k_red via MFMA ----
// Per (b,h): KV[d][e] = sum_s kh[s][d]*vh[s][e]. Block = 256 s-rows, K-tiles of 32.
#define KV_CHUNK 256
#define KV_TILE 32
__global__ __launch_bounds__(256) void kv_kernel(const unsigned short* __restrict__ kh,
                                                 const unsigned short* __restrict__ vh,
                                                 float* __restrict__ kv,
                                                 float* __restrict__ kred) {
    __shared__ unsigned short khT[64][40];
    __shared__ unsigned short vhT[64][40];

    const int t = threadIdx.x;
    const int w = t >> 6;
    const int l15 = t & 15;
    const int g = (t >> 4) & 3;
    const int b = blockIdx.z, h = blockIdx.y;
    const int s0 = blockIdx.x * KV_CHUNK;

    const int s_i = t >> 3;
    const int d0 = (t & 7) * 8;

    const size_t gbase = ((size_t)b * SEQ + s0 + s_i) * DM + h * DEPTH + d0;

    short8 ones;
    #pragma unroll
    for (int i = 0; i < 8; ++i) ones[i] = (short)0x3F80;  // bf16 1.0

    floatx4 acc[5] = {};

    int4 kr = *(const int4*)(kh + gbase);
    int4 vr = *(const int4*)(vh + gbase);

    #pragma unroll
    for (int tile = 0; tile < KV_CHUNK / KV_TILE; ++tile) {
        {
            const unsigned short* kk = (const unsigned short*)&kr;
            const unsigned short* vv = (const unsigned short*)&vr;
            #pragma unroll
            for (int i = 0; i < 8; ++i) khT[d0 + i][s_i] = kk[i];
            #pragma unroll
            for (int i = 0; i < 8; ++i) vhT[d0 + i][s_i] = vv[i];
        }
        if (tile + 1 < KV_CHUNK / KV_TILE) {
            size_t off = gbase + (size_t)(tile + 1) * KV_TILE * DM;
            kr = *(const int4*)(kh + off);
            vr = *(const int4*)(vh + off);
        }
        __syncthreads();

        short8 af = *(const short8*)&khT[w * 16 + l15][g * 8];
        short8 bf0 = *(const short8*)&vhT[0 * 16 + l15][g * 8];
        short8 bf1 = *(const short8*)&vhT[1 * 16 + l15][g * 8];
        short8 bf2 = *(const short8*)&vhT[2 * 16 + l15][g * 8];
        short8 bf3 = *(const short8*)&vhT[3 * 16 + l15][g * 8];
        acc[0] = __builtin_amdgcn_mfma_f32_16x16x32_bf16(af, bf0, acc[0], 0, 0, 0);
        acc[1] = __builtin_amdgcn_mfma_f32_16x16x32_bf16(af, bf1, acc[1], 0, 0, 0);
        acc[2] = __builtin_amdgcn_mfma_f32_16x16x32_bf16(af, bf2, acc[2], 0, 0, 0);
        acc[3] = __builtin_amdgcn_mfma_f32_16x16x32_bf16(af, ones, acc[3], 0, 0, 0);
        acc[4] = __builtin_amdgcn_mfma_f32_16x16x32_bf16(af, bf3, acc[4], 0, 0, 0);
        __syncthreads();
    }

    float* kvp = kv + (size_t)(b * HEADS + h) * (DEPTH * DEPTH);
    #pragma unroll
    for (int j = 0; j < 4; ++j) {
        int drow = w * 16 + g * 4 + j;
        atomicAdd(&kvp[drow * DEPTH + 0 * 16 + l15], acc[0][j]);
        atomicAdd(&kvp[drow * DEPTH + 1 * 16 + l15], acc[1][j]);
        atomicAdd(&kvp[drow * DEPTH + 2 * 16 + l15], acc[2][j]);
        atomicAdd(&kvp[drow * DEPTH + 3 * 16 + l15], acc[4][j]);
    }
    if (l15 == 0) {
        float* krp = kred + (b * HEADS + h) * DEPTH;
        #pragma unroll
        for (int j = 0; j < 4; ++j)
            atomicAdd(&krp[w * 16 + g * 4 + j], acc[3][j]);
    }
}

// ---- out via MFMA: per (b,h): out[s][e] = (qh[s][:] @ KV[:][e]) / (qh[s][:] @ (kred+eps)) ----
__global__ __launch_bounds__(256) void out_kernel(const unsigned short* __restrict__ qh,
                                                  const float* __restrict__ kv,
                                                  const float* __restrict__ kred,
                                                  float* __restrict__ out) {
    __shared__ unsigned short Qs[256 * 64];    // 32 KiB, chunk-XOR swizzled
    __shared__ unsigned short KVTs[80][72];    // pad-72 (2-way alias = free)

    const int t = threadIdx.x;
    const int l = t & 63;
    const int w = t >> 6;
    const int l15 = l & 15;
    const int g = l >> 4;
    const int b = blockIdx.z, h = blockIdx.y;
    const int s0 = blockIdx.x * 256;
    const int wr = w * 64;

    const size_t qbase = ((size_t)b * SEQ + s0) * DM + h * DEPTH;
    #pragma unroll
    for (int i = 0; i < 8; ++i) {
        int c = i * 256 + t;
        int r = c >> 3;
        int gp = c & 7;
        int gd = gp ^ (r & 7);
        const unsigned short* gsrc = qh + qbase + (size_t)r * DM + gd * 8;
        unsigned short* ldst = Qs + ((size_t)i * 256 + w * 64) * 8;
        gl_lds16(gsrc, ldst);
    }

    const float* kvp = kv + (size_t)(b * HEADS + h) * (DEPTH * DEPTH);
    const float* krp = kred + (size_t)(b * HEADS + h) * DEPTH;
    #pragma unroll
    for (int j = 0; j < 20; ++j) {
        int f = j * 256 + t;
        int e = f >> 6, d = f & 63;
        float val = (e < 64) ? kvp[d * DEPTH + e]
                  : (e == 64 ? (krp[d] + 1e-8f) : 0.0f);
        KVTs[e][d] = f2bf(val);
    }

    __syncthreads();

    short8 af[2][4], bfr[2][5];
    #pragma unroll
    for (int kk = 0; kk < 2; ++kk) {
        #pragma unroll
        for (int m = 0; m < 4; ++m) {
            int r = wr + m * 16 + l15;
            int ch = (kk * 4 + g) ^ (r & 7);
            af[kk][m] = *(const short8*)(Qs + r * 64 + ch * 8);
        }
        #pragma unroll
        for (int n = 0; n < 5; ++n)
            bfr[kk][n] = *(const short8*)&KVTs[n * 16 + l15][kk * 32 + g * 8];
    }

    floatx4 acc[4][5] = {};
    #pragma unroll
    for (int kk = 0; kk < 2; ++kk)
        #pragma unroll
        for (int m = 0; m < 4; ++m)
            #pragma unroll
            for (int n = 0; n < 5; ++n)
                acc[m][n] = __builtin_amdgcn_mfma_f32_16x16x32_bf16(af[kk][m], bfr[kk][n], acc[m][n], 0, 0, 0);

    float* op = out + ((size_t)b * SEQ + s0) * DM + h * DEPTH;
    #pragma unroll
    for (int m = 0; m < 4; ++m) {
        #pragma unroll
        for (int j = 0; j < 4; ++j) {
            float den = __shfl(acc[m][4][j], l & 48);
            float z = 1.0f / den;
            int row = wr + m * 16 + g * 4 + j;
            #pragma unroll
            for (int n = 0; n < 4; ++n)
                op[(size_t)row * DM + n * 16 + l15] = acc[m][n][j] * z;
        }
    }
}

extern "C" void kernel_launch(void* const* d_in, const int* in_sizes, int n_in,
                              void* d_out, int out_size, void* d_ws, size_t ws_size,
                              hipStream_t stream) {
    const float* q  = (const float*)d_in[0];
    const float* k  = (const float*)d_in[1];
    const float* v  = (const float*)d_in[2];
    const float* wq = (const float*)d_in[3];
    const float* bq = (const float*)d_in[4];
    const float* wk = (const float*)d_in[5];
    const float* bk = (const float*)d_in[6];
    const float* wv = (const float*)d_in[7];
    const float* bv = (const float*)d_in[8];
    float* out = (float*)d_out;

    char* ws = (char*)d_ws;
    const size_t sz_h = (size_t)MROWS * DM * 2;                 // 32 MiB each (bf16)
    unsigned short* qh  = (unsigned short*)(ws);
    unsigned short* kh  = (unsigned short*)(ws + sz_h);
    unsigned short* vh  = (unsigned short*)(ws + 2 * sz_h);
    unsigned short* wqT = (unsigned short*)(ws + 3 * sz_h);
    unsigned short* wkT = wqT + DM * DM;
    unsigned short* wvT = wkT + DM * DM;
    float* kvbuf   = (float*)(ws + 3 * sz_h + (size_t)3 * DM * DM * 2);
    float* kredbuf = kvbuf + BATCH * HEADS * DEPTH * DEPTH;

    hipMemsetAsync(kvbuf, 0,
                   (size_t)(BATCH * HEADS * DEPTH * DEPTH + BATCH * HEADS * DEPTH) * sizeof(float),
                   stream);

    wprep_kernel<<<dim3(DM * DM / 256, 3), 256, 0, stream>>>(wq, wk, wv, wqT, wkT, wvT);

    dim3 pgrid(DM / 128, MROWS / 64);   // (4 n-blocks, 512 m-blocks)
    proj_kernel<1><<<pgrid, 256, 0, stream>>>(q, wqT, bq, qh);
    proj_kernel<1><<<pgrid, 256, 0, stream>>>(k, wkT, bk, kh);
    proj_kernel<0><<<pgrid, 256, 0, stream>>>(v, wvT, bv, vh);

    kv_kernel<<<dim3(SEQ / KV_CHUNK, HEADS, BATCH), 256, 0, stream>>>(kh, vh, kvbuf, kredbuf);
    out_kernel<<<dim3(SEQ / 256, HEADS, BATCH), 256, 0, stream>>>(qh, kvbuf, kredbuf, out);
}